// Round 4
// baseline (514.213 us; speedup 1.0000x reference)
//
#include <hip/hip_runtime.h>

#define N_NODES 50000
#define E_EDGES 800000
#define IN_F 256
#define H_F 128
#define C_OUT 10
#define NCHUNK 8
#define CHW 16   // floats per feature chunk (64 B = 1 cache line)
#define NB_SCAN ((N_NODES + 255) / 256)   // 196, must be <= 256
static_assert(NB_SCAN <= 256, "scan2 assumes <=256 partials");

// ---------------- CSR build: count, scan, bucket ----------------

__global__ __launch_bounds__(256) void k_zero_cnt(int* __restrict__ cnt) {
    int i = blockIdx.x * 256 + threadIdx.x;
    if (i < N_NODES) cnt[i] = 0;
}

__global__ __launch_bounds__(256) void k_count(const int* __restrict__ dst,
                                               int* __restrict__ cnt) {
    int e = blockIdx.x * 256 + threadIdx.x;
    if (e < E_EDGES) atomicAdd(&cnt[dst[e]], 1);
}

__global__ __launch_bounds__(256) void k_scan1(const int* __restrict__ cnt,
                                               int* __restrict__ row_off,
                                               int* __restrict__ part) {
    __shared__ int sm[256];
    int tid = threadIdx.x;
    int i = blockIdx.x * 256 + tid;
    int v = (i < N_NODES) ? cnt[i] : 0;
    sm[tid] = v;
    __syncthreads();
#pragma unroll
    for (int off = 1; off < 256; off <<= 1) {
        int t = (tid >= off) ? sm[tid - off] : 0;
        __syncthreads();
        sm[tid] += t;
        __syncthreads();
    }
    if (i < N_NODES) row_off[i] = sm[tid] - v;   // exclusive
    if (tid == 255) part[blockIdx.x] = sm[255];  // block total
}

__global__ __launch_bounds__(256) void k_scan2(int* __restrict__ part) {
    __shared__ int sm[256];
    int tid = threadIdx.x;
    int v = (tid < NB_SCAN) ? part[tid] : 0;
    sm[tid] = v;
    __syncthreads();
#pragma unroll
    for (int off = 1; off < 256; off <<= 1) {
        int t = (tid >= off) ? sm[tid - off] : 0;
        __syncthreads();
        sm[tid] += t;
        __syncthreads();
    }
    if (tid < NB_SCAN) part[tid] = sm[tid] - v;  // exclusive
}

__global__ __launch_bounds__(256) void k_scan3(const int* __restrict__ cnt,
                                               const int* __restrict__ part,
                                               int* __restrict__ row_off,
                                               int* __restrict__ cursor,
                                               float* __restrict__ dinv) {
    int i = blockIdx.x * 256 + threadIdx.x;
    if (i >= N_NODES) return;
    int ro = row_off[i] + part[blockIdx.x];
    row_off[i] = ro;
    cursor[i] = ro;
    dinv[i] = rsqrtf((float)(cnt[i] + 1));
}

// permute edges into CSR slots; pack (src, weight) into one int2
__global__ __launch_bounds__(256) void k_bucket(const int* __restrict__ src,
                                                const int* __restrict__ dst,
                                                const float* __restrict__ dinv,
                                                int* __restrict__ cursor,
                                                int2* __restrict__ csr) {
    int e = blockIdx.x * 256 + threadIdx.x;
    if (e >= E_EDGES) return;
    int s = src[e], d = dst[e];
    int pos = atomicAdd(&cursor[d], 1);
    csr[pos] = make_int2(s, __float_as_int(dinv[s] * dinv[d]));
}

// ---------------- fused aggregate + mean + bias + relu ----------------
// XCD-chunked: block handles 4 nodes x 1 feature-chunk; chunk = blockIdx & 7
// so each XCD's gathers stay within a 3.2 MB slice of hW (L2-resident).
// Wave: 64 lanes = 4 edge slots x 16 features.

__global__ __launch_bounds__(256) void k_agg(const float* __restrict__ hW,
                                             const int* __restrict__ row_off,
                                             const int* __restrict__ cnt,
                                             const int2* __restrict__ csr,
                                             const float* __restrict__ dinv,
                                             const float* __restrict__ bias,
                                             float* __restrict__ h) {
    int chunk = blockIdx.x & (NCHUNK - 1);
    int nb    = blockIdx.x >> 3;
    int node  = nb * 4 + (threadIdx.x >> 6);
    if (node >= N_NODES) return;
    int lane = threadIdx.x & 63;
    int es = lane >> 4;          // edge slot 0..3
    int f  = lane & 15;          // feature within chunk
    int col = chunk * CHW + f;
    const float* tab = hW + col;

    int beg = row_off[node];
    int c = cnt[node];
    float acc = 0.0f;
    int j = es;
    for (; j + 4 < c; j += 8) {              // 2 edges in flight per lane
        int2 e0 = csr[beg + j];
        int2 e1 = csr[beg + j + 4];
        float v0 = tab[(size_t)e0.x * H_F];
        float v1 = tab[(size_t)e1.x * H_F];
        acc = fmaf(__int_as_float(e1.y), v1,
                   fmaf(__int_as_float(e0.y), v0, acc));
    }
    if (j < c) {
        int2 e0 = csr[beg + j];
        acc = fmaf(__int_as_float(e0.y), tab[(size_t)e0.x * H_F], acc);
    }
    // combine the 4 edge slots
    acc += __shfl_xor(acc, 16, 64);
    acc += __shfl_xor(acc, 32, 64);
    // self loop + mean + bias + relu
    float iv = dinv[node];
    float selfv = hW[(size_t)node * H_F + col];
    acc = fmaf(selfv, iv * iv, acc);
    float rd = 1.0f / (float)(c + 1);
    float o = fmaxf(fmaf(acc, rd, bias[col]), 0.0f);
    if (lane < 16) h[(size_t)node * H_F + col] = o;
}

// ---------------- fp32 GEMM: C[M x 128] = A[M x K] @ B[K x 128] ----------------
// 64x128 tile per 256-thread block, BK=32, 4x8 per thread.

template <int K>
__global__ __launch_bounds__(256, 4) void k_gemm(const float* __restrict__ A,
                                                 const float* __restrict__ B,
                                                 float* __restrict__ C) {
    __shared__ float As[32][68];
    __shared__ float Bs[32][132];
    const int tid = threadIdx.x;
    const int brow = blockIdx.x * 64;
    const int tr4 = (tid >> 4) * 4;
    const int tc4 = (tid & 15) * 4;
    const int ar  = tid >> 2;
    const int akk = (tid & 3) * 4;
    const int bqr = tid >> 5;
    const int bqc = (tid & 31) * 4;

    float acc[4][8] = {};
    const int arow_g = brow + ar;
    const bool arow_ok = arow_g < N_NODES;
    const float* Arow = A + (size_t)arow_g * K;

    for (int kt = 0; kt < K; kt += 32) {
        float4 va0 = make_float4(0.f, 0.f, 0.f, 0.f), va1 = va0;
        if (arow_ok) {
            va0 = *(const float4*)(Arow + kt + akk);
            va1 = *(const float4*)(Arow + kt + akk + 16);
        }
        As[akk + 0][ar] = va0.x;  As[akk + 1][ar] = va0.y;
        As[akk + 2][ar] = va0.z;  As[akk + 3][ar] = va0.w;
        As[akk + 16][ar] = va1.x; As[akk + 17][ar] = va1.y;
        As[akk + 18][ar] = va1.z; As[akk + 19][ar] = va1.w;
#pragma unroll
        for (int q = 0; q < 4; ++q) {
            int r = q * 8 + bqr;
            *(float4*)&Bs[r][bqc] = *(const float4*)(B + (size_t)(kt + r) * H_F + bqc);
        }
        __syncthreads();
#pragma unroll
        for (int k = 0; k < 32; ++k) {
            float4 a4 = *(const float4*)&As[k][tr4];
            float4 b0 = *(const float4*)&Bs[k][tc4];
            float4 b1 = *(const float4*)&Bs[k][tc4 + 64];
            float av[4] = {a4.x, a4.y, a4.z, a4.w};
            float bv[8] = {b0.x, b0.y, b0.z, b0.w, b1.x, b1.y, b1.z, b1.w};
#pragma unroll
            for (int i = 0; i < 4; ++i)
#pragma unroll
                for (int jj = 0; jj < 8; ++jj)
                    acc[i][jj] = fmaf(av[i], bv[jj], acc[i][jj]);
        }
        __syncthreads();
    }
#pragma unroll
    for (int i = 0; i < 4; ++i) {
        int gr = brow + tr4 + i;
        if (gr < N_NODES) {
            float4 c0 = {acc[i][0], acc[i][1], acc[i][2], acc[i][3]};
            float4 c1 = {acc[i][4], acc[i][5], acc[i][6], acc[i][7]};
            *(float4*)(C + (size_t)gr * H_F + tc4) = c0;
            *(float4*)(C + (size_t)gr * H_F + tc4 + 64) = c1;
        }
    }
}

// ---------------- final projection: out[N x 10] = H @ Wc + bc ----------------

__global__ __launch_bounds__(256) void k_out(const float* __restrict__ Hf,
                                             const float* __restrict__ Wc,
                                             const float* __restrict__ bc,
                                             float* __restrict__ out) {
    int id = blockIdx.x * 256 + threadIdx.x;
    if (id >= N_NODES * C_OUT) return;
    int row = id / C_OUT;
    int col = id - row * C_OUT;
    const float4* h4 = (const float4*)(Hf + (size_t)row * H_F);
    float sum = bc[col];
#pragma unroll
    for (int k4 = 0; k4 < 32; ++k4) {
        float4 v = h4[k4];
        sum = fmaf(v.x, Wc[(k4 * 4 + 0) * C_OUT + col], sum);
        sum = fmaf(v.y, Wc[(k4 * 4 + 1) * C_OUT + col], sum);
        sum = fmaf(v.z, Wc[(k4 * 4 + 2) * C_OUT + col], sum);
        sum = fmaf(v.w, Wc[(k4 * 4 + 3) * C_OUT + col], sum);
    }
    out[id] = sum;
}

// ---------------- launch ----------------

extern "C" void kernel_launch(void* const* d_in, const int* in_sizes, int n_in,
                              void* d_out, int out_size, void* d_ws, size_t ws_size,
                              hipStream_t stream) {
    const float* x  = (const float*)d_in[0];
    const int*   ei = (const int*)d_in[1];
    const float* W1 = (const float*)d_in[2];
    const float* b1 = (const float*)d_in[3];
    const float* W2 = (const float*)d_in[4];
    const float* b2 = (const float*)d_in[5];
    const float* Wc = (const float*)d_in[6];
    const float* bc = (const float*)d_in[7];
    const int* esrc = ei;
    const int* edst = ei + E_EDGES;

    char* ws = (char*)d_ws;
    int*   cnt     = (int*)ws;                    ws += sizeof(int) * N_NODES;
    int*   row_off = (int*)ws;                    ws += sizeof(int) * N_NODES;
    int*   cursor  = (int*)ws;                    ws += sizeof(int) * N_NODES;
    float* dinv    = (float*)ws;                  ws += sizeof(float) * N_NODES;
    int*   part    = (int*)ws;                    ws += sizeof(int) * 256;
    ws = (char*)(((size_t)ws + 15) & ~(size_t)15);
    int2*  csr     = (int2*)ws;                   ws += sizeof(int2) * E_EDGES;
    float* bufA    = (float*)ws;                  ws += sizeof(float) * (size_t)N_NODES * H_F;
    float* bufC    = (float*)ws;
    float* out = (float*)d_out;

    const int gN = (N_NODES + 255) / 256;
    const int gE = (E_EDGES + 255) / 256;
    const int gAgg = ((N_NODES + 3) / 4) * NCHUNK;
    const int gGemm = (N_NODES + 63) / 64;

    // CSR build (graph fixed per call; rebuilt every call for determinism)
    k_zero_cnt<<<gN, 256, 0, stream>>>(cnt);
    k_count<<<gE, 256, 0, stream>>>(edst, cnt);
    k_scan1<<<NB_SCAN, 256, 0, stream>>>(cnt, row_off, part);
    k_scan2<<<1, 256, 0, stream>>>(part);
    k_scan3<<<NB_SCAN, 256, 0, stream>>>(cnt, part, row_off, cursor, dinv);
    k_bucket<<<gE, 256, 0, stream>>>(esrc, edst, dinv, cursor, csr);

    // layer 1
    k_gemm<IN_F><<<gGemm, 256, 0, stream>>>(x, W1, bufA);
    k_agg<<<gAgg, 256, 0, stream>>>(bufA, row_off, cnt, csr, dinv, b1, bufC);

    // layer 2
    k_gemm<H_F><<<gGemm, 256, 0, stream>>>(bufC, W2, bufA);
    k_agg<<<gAgg, 256, 0, stream>>>(bufA, row_off, cnt, csr, dinv, b2, bufC);

    // classifier
    k_out<<<(N_NODES * C_OUT + 255) / 256, 256, 0, stream>>>(bufC, Wc, bc, out);
}